// Round 3
// baseline (589.358 us; speedup 1.0000x reference)
//
#include <hip/hip_runtime.h>
#include <math.h>

#define BB 16
#define CC 64
#define HH 128
#define WW 256
#define HWs 32768      // HH*WW
#define NN 524288      // BB*HH*WW
#define KMAX 8192
#define RCAP 65536     // tile-root list capacity per z
#define INV 0xFFFFFFFFu

// tile: full batch depth x 8h x 32w = 4096 voxels, 512 threads
#define TILE_H 8
#define TILE_W 32
#define TVOX 4096
#define TPB 512
#define NROWS 128      // BB * TILE_H rows of 32 w-bits
#define NWEDGE 14336   // 7 internal w-boundaries * 16b * 128h
#define NHEDGE 61440   // 15 internal h-boundaries * 16b * 256w
#define NEDGE  75776

// ---- workspace layout (bytes) ----
#define OFF_CMEAN    0                                   // f32 [3][NN]
#define OFF_PARENT   (OFF_CMEAN   + 3*NN*4)              // u32 [3][NN]
#define OFF_DENSE    (OFF_PARENT  + 3*NN*4)              // u32 [3][NN] (sparse: only roots)
#define OFF_ROOTLIST (OFF_DENSE   + 3*NN*4)              // u32 [3][RCAP] (not zeroed)
#define OFF_COUNTS   (OFF_ROOTLIST+ 3*RCAP*4)            // i32 [3][BB][KMAX]   <- zeroed from here
#define OFF_ROOTLAB  (OFF_COUNTS  + 3*BB*KMAX*4)         // u32 [3][KMAX]
#define OFF_MMKEY    (OFF_ROOTLAB + 3*KMAX*4)            // u32 [3][BB][2] (~minkey,maxkey), both atomicMax
#define OFF_K        (OFF_MMKEY   + 3*BB*2*4)            // u32 [3] (+pad)
#define OFF_RCNT     (OFF_K       + 16)                  // u32 [3] (+pad)
#define OFF_BEST     (OFF_RCNT    + 16)                  // u32 [3][BB]
#define OFF_CENT     (OFF_BEST    + 3*BB*4)              // i32 [3][BB][3]
#define OFF_END      (OFF_CENT    + 3*BB*3*4)

// monotone float<->uint key (order-preserving incl. negatives)
__device__ __forceinline__ unsigned f2key(float f) {
    unsigned u = __float_as_uint(f);
    return (u & 0x80000000u) ? ~u : (u | 0x80000000u);
}
__device__ __forceinline__ float key2f(unsigned k) {
    unsigned u = (k & 0x80000000u) ? (k ^ 0x80000000u) : ~k;
    return __uint_as_float(u);
}

// ---- union-find, links always point to LARGER index => root = max linear idx ----
__device__ unsigned uf_find(unsigned* p, unsigned i) {
    while (true) {
        unsigned pi = ((volatile unsigned*)p)[i];
        if (pi == i) return i;
        unsigned gp = ((volatile unsigned*)p)[pi];
        if (gp != pi) ((volatile unsigned*)p)[i] = gp;  // path halving (monotone, safe)
        i = pi;
    }
}
__device__ void uf_union(unsigned* p, unsigned a, unsigned b) {
    while (true) {
        a = uf_find(p, a);
        b = uf_find(p, b);
        if (a == b) return;
        if (a < b) { unsigned t = a; a = b; b = t; }   // a = max root
        unsigned old = atomicCAS(&p[b], b, a);
        if (old == b) return;
        b = old;
    }
}

// ---- LDS union-find (same invariants, shared-memory atomics) ----
__device__ __forceinline__ unsigned lfind(unsigned* p, unsigned i) {
    while (true) {
        unsigned pi = ((volatile unsigned*)p)[i];
        if (pi == i) return i;
        unsigned gp = ((volatile unsigned*)p)[pi];
        if (gp != pi) ((volatile unsigned*)p)[i] = gp;
        i = pi;
    }
}
__device__ void lunion(unsigned* p, unsigned a, unsigned b) {
    while (true) {
        a = lfind(p, a);
        b = lfind(p, b);
        if (a == b) return;
        if (a < b) { unsigned t = a; a = b; b = t; }
        unsigned old = atomicCAS(&p[b], b, a);
        if (old == b) return;
        b = old;
    }
}

// channel mean + per-sample min/max, ONE z per dispatch (template => distinct
// kernel names in rocprof, so the top-5 list stops being saturated by cmean
// replicas and reveals the downstream heavy hitters).
// Per-element summation tree identical to previous rounds (4 mod-4 c-class
// accumulators, combined ((a0+a1)+(a2+a3))/64) => bit-identical cmean.
template<int Z>
__global__ void k_cmean_z(const float* __restrict__ x, float* __restrict__ cmean,
                          unsigned* __restrict__ mmkey) {
    int b = blockIdx.y, t = threadIdx.x;
    int hw = blockIdx.x * 1024 + t * 4;
    const float* px = x + (size_t)b * CC * HWs + hw;
    float4 a0 = make_float4(0.f, 0.f, 0.f, 0.f), a1 = a0, a2 = a0, a3 = a0;
#pragma unroll
    for (int c = 0; c < CC; c += 4) {
        float4 v0 = *reinterpret_cast<const float4*>(px + (size_t)(c + 0) * HWs);
        float4 v1 = *reinterpret_cast<const float4*>(px + (size_t)(c + 1) * HWs);
        float4 v2 = *reinterpret_cast<const float4*>(px + (size_t)(c + 2) * HWs);
        float4 v3 = *reinterpret_cast<const float4*>(px + (size_t)(c + 3) * HWs);
        a0.x += v0.x; a0.y += v0.y; a0.z += v0.z; a0.w += v0.w;
        a1.x += v1.x; a1.y += v1.y; a1.z += v1.z; a1.w += v1.w;
        a2.x += v2.x; a2.y += v2.y; a2.z += v2.z; a2.w += v2.w;
        a3.x += v3.x; a3.y += v3.y; a3.z += v3.z; a3.w += v3.w;
    }
    const float inv = 1.f / 64.f;   // /64 exact pow2
    float4 s;
    s.x = ((a0.x + a1.x) + (a2.x + a3.x)) * inv;
    s.y = ((a0.y + a1.y) + (a2.y + a3.y)) * inv;
    s.z = ((a0.z + a1.z) + (a2.z + a3.z)) * inv;
    s.w = ((a0.w + a1.w) + (a2.w + a3.w)) * inv;
    float* cm = cmean + (size_t)Z * NN + (size_t)b * HWs + hw;
    *reinterpret_cast<float4*>(cm) = s;

    float mn = fminf(fminf(s.x, s.y), fminf(s.z, s.w));
    float mx = fmaxf(fmaxf(s.x, s.y), fmaxf(s.z, s.w));
    for (int o = 32; o; o >>= 1) {
        mn = fminf(mn, __shfl_down(mn, o));
        mx = fmaxf(mx, __shfl_down(mx, o));
    }
    __shared__ float smn[4], smx[4];
    int wid = t >> 6, lane = t & 63;
    if (lane == 0) { smn[wid] = mn; smx[wid] = mx; }
    __syncthreads();
    if (t == 0) {
        mn = fminf(fminf(smn[0], smn[1]), fminf(smn[2], smn[3]));
        mx = fmaxf(fmaxf(smx[0], smx[1]), fmaxf(smx[2], smx[3]));
        atomicMax(&mmkey[(Z * BB + b) * 2 + 0], ~f2key(mn));
        atomicMax(&mmkey[(Z * BB + b) * 2 + 1], f2key(mx));
    }
}

// fused: normalize -> mask -> LOCAL run-based CCL over a [16b x 8h x 32w] tile.
// 512 threads (8 phases). Also emits a compacted global list of tile-root
// voxel indices so the downstream compress pass touches only roots, not NN.
__global__ void __launch_bounds__(TPB) k_mask_ccl(const float* __restrict__ cmean,
                                                  const unsigned* __restrict__ mmkey,
                                                  unsigned* __restrict__ parent_all,
                                                  unsigned* __restrict__ rootlist,
                                                  unsigned* __restrict__ rootcnt) {
    int z = blockIdx.z;
    int h0 = blockIdx.y * TILE_H;
    int w0 = blockIdx.x * TILE_W;
    int t = threadIdx.x;
    int lane = t & 63;
    __shared__ unsigned sp[TVOX];
    __shared__ unsigned rowmask[NROWS];
    __shared__ float smn[BB], smx[BB];
    __shared__ unsigned lcnt, sbase;
    if (t == 0) lcnt = 0;
    if (t < BB) {
        smn[t] = key2f(~mmkey[(z * BB + t) * 2 + 0]);
        smx[t] = key2f(mmkey[(z * BB + t) * 2 + 1]);
    }
    __syncthreads();
#pragma unroll
    for (int ph = 0; ph < TVOX / TPB; ph++) {
        int li = ph * TPB + t;
        int lb = li >> 8, lh = (li >> 5) & 7, lw = li & 31;
        unsigned gi = lb * HWs + (h0 + lh) * WW + (w0 + lw);
        float c = cmean[(size_t)z * NN + gi];
        bool mkd = (c - smn[lb]) / (smx[lb] - smn[lb]) >= 0.4f;
        unsigned long long bal = __ballot(mkd);
        unsigned m = (lane < 32) ? (unsigned)bal : (unsigned)(bal >> 32);
        int row = li >> 5;
        if ((lane & 31) == 0) rowmask[row] = m;
        unsigned v = INV;
        if (mkd) {
            int j = __ffsll(~((unsigned long long)m >> lw)) - 1;  // trailing-ones >=1
            v = (unsigned)((row << 5) + lw + j - 1);              // run root (run max)
        }
        sp[li] = v;
    }
    __syncthreads();
#pragma unroll
    for (int ph = 0; ph < TVOX / TPB; ph++) {
        int li = ph * TPB + t;
        int row = li >> 5, lw = li & 31;
        unsigned m = rowmask[row];
        if (!((m >> lw) & 1)) continue;
        int lh = row & 7;
        if (lh < TILE_H - 1) {                       // h-edge, row -> row+1
            unsigned m2 = rowmask[row + 1];
            unsigned ov = m & m2;
            bool leader = ((ov >> lw) & 1) && (lw == 0 || !((ov >> (lw - 1)) & 1));
            if (leader) {
                int j2 = __ffsll(~((unsigned long long)m2 >> lw)) - 1;
                lunion(sp, sp[li], (unsigned)(((row + 1) << 5) + lw + j2 - 1));
            }
        }
        if (row < NROWS - 8) {                       // b-edge, row -> row+8
            unsigned m2 = rowmask[row + 8];
            unsigned ov = m & m2;
            bool leader = ((ov >> lw) & 1) && (lw == 0 || !((ov >> (lw - 1)) & 1));
            if (leader) {
                int j2 = __ffsll(~((unsigned long long)m2 >> lw)) - 1;
                lunion(sp, sp[li], (unsigned)(((row + 8) << 5) + lw + j2 - 1));
            }
        }
    }
    __syncthreads();
    // pointer-jump flatten: tree static now; races only move entries rootward
#pragma unroll
    for (int it = 0; it < 4; it++) {
#pragma unroll
        for (int ph = 0; ph < TVOX / TPB; ph++) {
            int li = ph * TPB + t;
            unsigned v = sp[li];
            if (v != INV) {
                unsigned w = sp[v];
                if (w != v) sp[li] = w;
            }
        }
    }
    __syncthreads();
    unsigned myroot[TVOX / TPB];
    unsigned myoff[TVOX / TPB];
    int nmy = 0;
#pragma unroll
    for (int ph = 0; ph < TVOX / TPB; ph++) {
        int li = ph * TPB + t;
        int lb = li >> 8, lh = (li >> 5) & 7, lw = li & 31;
        unsigned gi = lb * HWs + (h0 + lh) * WW + (w0 + lw);
        unsigned v = sp[li];
        if (v != INV) {
            unsigned r = v;
            while (sp[r] != r) r = sp[r];           // short after flatten
            int rb = r >> 8, rh = (r >> 5) & 7, rw = r & 31;
            v = rb * HWs + (h0 + rh) * WW + (w0 + rw);
            if (r == (unsigned)li) {                // tile root -> record
                myroot[nmy] = gi;
                myoff[nmy] = atomicAdd(&lcnt, 1u);
                nmy++;
            }
        }
        parent_all[(size_t)z * NN + gi] = v;
    }
    __syncthreads();
    if (t == 0) sbase = atomicAdd(&rootcnt[z], lcnt);
    __syncthreads();
    for (int k = 0; k < nmy; k++) {
        unsigned idx = sbase + myoff[k];
        if (idx < RCAP) rootlist[(size_t)z * RCAP + idx] = myroot[k];
    }
}

// global unions only across tile boundaries (tile-root handles), run-leader dedup
__global__ void k_merge_bnd(unsigned* __restrict__ parent_all) {
    int z = blockIdx.y;
    unsigned* p = parent_all + (size_t)z * NN;
    int e = blockIdx.x * 256 + threadIdx.x;
    if (e >= NEDGE) return;
    unsigned i, j;
    bool lead = true;
    if (e < NWEDGE) {
        int k = e % 7, rest = e / 7;           // rest = b*128 + h
        int h = rest & (HH - 1), b = rest >> 7;
        int w = k * TILE_W + (TILE_W - 1);
        i = b * HWs + h * WW + w; j = i + 1;
        if ((h & (TILE_H - 1)) != 0)           // prev-h pair in same tiles?
            if (p[i - WW] != INV && p[j - WW] != INV) lead = false;
    } else {
        int e2 = e - NWEDGE;
        int k = e2 % 15, rest = e2 / 15;       // rest = b*256 + w
        int w = rest & (WW - 1), b = rest >> 8;
        int h = k * TILE_H + (TILE_H - 1);
        i = b * HWs + h * WW + w; j = i + WW;
        if ((w & (TILE_W - 1)) != 0)
            if (p[i - 1] != INV && p[j - 1] != INV) lead = false;
    }
    if (lead) {
        unsigned pi = p[i], pj = p[j];
        if (pi != INV && pj != INV) uf_union(p, pi, pj);
    }
}

// compress ONLY tile roots (p[t] -> global root) + dense-id the global roots.
// After this, root(voxel i) == p[p[i]] exactly, with no NN-wide write pass.
__global__ void k_rootcompress(unsigned* __restrict__ parent_all,
                               const unsigned* __restrict__ rootlist,
                               const unsigned* __restrict__ rootcnt,
                               unsigned* __restrict__ dense_all,
                               unsigned* __restrict__ rootlab, unsigned* __restrict__ Kc) {
    int z = blockIdx.y;
    unsigned* p = parent_all + (size_t)z * NN;
    unsigned cnt = rootcnt[z]; if (cnt > RCAP) cnt = RCAP;
    for (unsigned j = blockIdx.x * 256 + threadIdx.x; j < cnt; j += gridDim.x * 256) {
        unsigned r = rootlist[(size_t)z * RCAP + j];
        unsigned g = uf_find(p, r);
        p[r] = g;
        if (g == r) {
            unsigned id = atomicAdd(&Kc[z], 1u);
            if (id >= KMAX) id = KMAX - 1;   // never expected
            dense_all[(size_t)z * NN + g] = id;
            rootlab[z * KMAX + id] = g;
        }
    }
}

// per-slice per-component counts, wave-aggregated atomics; root = p[p[i]]
__global__ void k_count(const unsigned* __restrict__ parent_all,
                        const unsigned* __restrict__ dense_all, int* __restrict__ counts) {
    int z = blockIdx.y;
    const unsigned* p = parent_all + (size_t)z * NN;
    const unsigned* d = dense_all + (size_t)z * NN;
    int i = blockIdx.x * 256 + threadIdx.x;
    int b = i >> 15;   // uniform across the wave (64 | HWs)
    unsigned pi = p[i];
    bool valid = (pi != INV);
    int id = valid ? (int)d[p[pi]] : -1;
    int lane = threadIdx.x & 63;
    int* crow = counts + ((size_t)z * BB + b) * KMAX;
    unsigned long long rem = __ballot(valid);
    while (rem) {
        int leader = __ffsll(rem) - 1;
        int lid = __shfl(id, leader);
        unsigned long long m = __ballot(valid && id == lid) & rem;
        if (lane == leader) atomicAdd(&crow[lid], (int)__popcll(m));
        rem &= ~m;
    }
}

// per-slice argmax: max count, tie -> smallest root label (== reference argmax semantics)
__global__ void k_best(const int* __restrict__ counts, const unsigned* __restrict__ rootlab,
                       const unsigned* __restrict__ Kc, unsigned* __restrict__ best) {
    int z = blockIdx.y, b = blockIdx.x, t = threadIdx.x;
    const int* crow = counts + ((size_t)z * BB + b) * KMAX;
    const unsigned* rl = rootlab + z * KMAX;
    unsigned K = Kc[z]; if (K > KMAX) K = KMAX;
    int bc = -1; unsigned brl = INV; int bj = 0;
    for (unsigned j = t; j < K; j += blockDim.x) {
        int c = crow[j]; unsigned r = rl[j];
        if (c > bc || (c == bc && r < brl)) { bc = c; brl = r; bj = (int)j; }
    }
    __shared__ int sc[256]; __shared__ unsigned sr[256]; __shared__ int sj[256];
    sc[t] = bc; sr[t] = brl; sj[t] = bj;
    __syncthreads();
    for (int o = 128; o; o >>= 1) {
        if (t < o) {
            int c2 = sc[t + o]; unsigned r2 = sr[t + o];
            if (c2 > sc[t] || (c2 == sc[t] && r2 < sr[t])) { sc[t] = c2; sr[t] = r2; sj[t] = sj[t + o]; }
        }
        __syncthreads();
    }
    if (t == 0) best[z * BB + b] = (unsigned)sj[0];
}

// masked normalized output + integer centroid sums; root = p[p[i]]
__global__ void k_result(const float* __restrict__ cmean, const unsigned* __restrict__ parent_all,
                         const unsigned* __restrict__ dense_all, const unsigned* __restrict__ mmkey,
                         const unsigned* __restrict__ best, float* __restrict__ out,
                         int* __restrict__ cent) {
    int z = blockIdx.y;
    int i = blockIdx.x * 256 + threadIdx.x;
    int b = i >> 15;
    const unsigned* p = parent_all + (size_t)z * NN;
    unsigned pi = p[i];
    bool big = false;
    if (pi != INV) big = (dense_all[(size_t)z * NN + p[pi]] == best[z * BB + b]);
    float mn = key2f(~mmkey[(z * BB + b) * 2 + 0]);
    float mx = key2f(mmkey[(z * BB + b) * 2 + 1]);
    float c = cmean[(size_t)z * NN + i];
    float v = (c - mn) / (mx - mn);
    out[32 + (size_t)z * NN + i] = big ? v : 0.f;

    int c1 = big ? 1 : 0;
    int ch = big ? ((i >> 8) & (HH - 1)) : 0;
    int cw = big ? (i & (WW - 1)) : 0;
    for (int o = 32; o; o >>= 1) {
        c1 += __shfl_down(c1, o); ch += __shfl_down(ch, o); cw += __shfl_down(cw, o);
    }
    __shared__ int s0[4], s1[4], s2[4];
    int wid = threadIdx.x >> 6, lane = threadIdx.x & 63;
    if (lane == 0) { s0[wid] = c1; s1[wid] = ch; s2[wid] = cw; }
    __syncthreads();
    if (threadIdx.x == 0) {
        c1 = s0[0] + s0[1] + s0[2] + s0[3];
        ch = s1[0] + s1[1] + s1[2] + s1[3];
        cw = s2[0] + s2[1] + s2[2] + s2[3];
        int* ct = cent + (z * BB + b) * 3;
        atomicAdd(&ct[0], c1); atomicAdd(&ct[1], ch); atomicAdd(&ct[2], cw);
    }
}

__global__ void k_final(const int* __restrict__ cent, float* __restrict__ out) {
    int b = threadIdx.x;
    if (b >= BB) return;
    const float PI = (float)M_PI;  // f32(np.pi)
    float th[3], ph[3];
    for (int z = 0; z < 3; z++) {
        const int* ct = cent + (z * BB + b) * 3;
        float cnt = (float)ct[0];
        float hm = (float)ct[1] / cnt;   // integer sums exact in f32 (< 2^24)
        float wm = (float)ct[2] / cnt;
        ph[z] = (0.5f - hm / (float)HH) * PI;
        th[z] = (wm / (float)WW - 0.5f) * 2.0f * PI;
    }
    auto dist = [PI](float t1, float p1, float t2, float p2) {
        float cosd = sinf(t1) * sinf(t2) + cosf(t1) * cosf(t2) * cosf(p1 - p2);
        float d = acosf(cosd);
        if (isnan(d)) d = 0.f;           // jnp.nan_to_num semantics
        return d / PI;
    };
    out[b]      = dist(th[0], ph[0], th[1], ph[1]);
    out[BB + b] = dist(th[1], ph[1], th[2], ph[2]);
}

extern "C" void kernel_launch(void* const* d_in, const int* in_sizes, int n_in,
                              void* d_out, int out_size, void* d_ws, size_t ws_size,
                              hipStream_t stream) {
    const float* x0 = (const float*)d_in[0];
    const float* x1 = (const float*)d_in[1];
    const float* x2 = (const float*)d_in[2];
    float* out = (float*)d_out;
    char* ws = (char*)d_ws;
    float*    cmean    = (float*)(ws + OFF_CMEAN);
    unsigned* parent   = (unsigned*)(ws + OFF_PARENT);
    unsigned* dense    = (unsigned*)(ws + OFF_DENSE);
    unsigned* rootlist = (unsigned*)(ws + OFF_ROOTLIST);
    int*      counts   = (int*)(ws + OFF_COUNTS);
    unsigned* rootlab  = (unsigned*)(ws + OFF_ROOTLAB);
    unsigned* mmkey    = (unsigned*)(ws + OFF_MMKEY);
    unsigned* Kc       = (unsigned*)(ws + OFF_K);
    unsigned* rootcnt  = (unsigned*)(ws + OFF_RCNT);
    unsigned* best     = (unsigned*)(ws + OFF_BEST);
    int*      cent     = (int*)(ws + OFF_CENT);

    hipMemsetAsync(ws + OFF_COUNTS, 0, OFF_END - OFF_COUNTS, stream);
    hipLaunchKernelGGL(k_cmean_z<0>, dim3(HWs / 1024, BB), dim3(256), 0, stream, x0, cmean, mmkey);
    hipLaunchKernelGGL(k_cmean_z<1>, dim3(HWs / 1024, BB), dim3(256), 0, stream, x1, cmean, mmkey);
    hipLaunchKernelGGL(k_cmean_z<2>, dim3(HWs / 1024, BB), dim3(256), 0, stream, x2, cmean, mmkey);
    hipLaunchKernelGGL(k_mask_ccl, dim3(WW / TILE_W, HH / TILE_H, 3), dim3(TPB), 0, stream,
                       cmean, mmkey, parent, rootlist, rootcnt);
    hipLaunchKernelGGL(k_merge_bnd, dim3((NEDGE + 255) / 256, 3), dim3(256), 0, stream, parent);
    hipLaunchKernelGGL(k_rootcompress, dim3(32, 3), dim3(256), 0, stream,
                       parent, rootlist, rootcnt, dense, rootlab, Kc);
    hipLaunchKernelGGL(k_count, dim3(NN / 256, 3), dim3(256), 0, stream, parent, dense, counts);
    hipLaunchKernelGGL(k_best, dim3(BB, 3), dim3(256), 0, stream, counts, rootlab, Kc, best);
    hipLaunchKernelGGL(k_result, dim3(NN / 256, 3), dim3(256), 0, stream,
                       cmean, parent, dense, mmkey, best, out, cent);
    hipLaunchKernelGGL(k_final, dim3(1), dim3(64), 0, stream, cent, out);
}

// Round 4
// 530.219 us; speedup vs baseline: 1.1115x; 1.1115x over previous
//
#include <hip/hip_runtime.h>
#include <math.h>

#define BB 16
#define CC 64
#define HH 128
#define WW 256
#define HWs 32768      // HH*WW
#define NN 524288      // BB*HH*WW
#define KMAX 8192
#define RCAP 65536     // tile-root list capacity per z
#define INV 0xFFFFFFFFu

// tile: full batch depth x 8h x 32w = 4096 voxels, 512 threads
#define TILE_H 8
#define TILE_W 32
#define TVOX 4096
#define TPB 512
#define NROWS 128      // BB * TILE_H rows of 32 w-bits

// tile-pair boundaries (for the wave-per-pair merge)
#define NPW 112        // 7 internal w-boundaries * 16 h-tiles
#define NPH 120        // 15 internal h-boundaries * 8 w-tiles
#define NPAIR 232

// ---- workspace layout (bytes) ----
#define OFF_CMEAN    0                                   // f32 [3][NN]
#define OFF_PARENT   (OFF_CMEAN   + 3*NN*4)              // u32 [3][NN]
#define OFF_DENSE    (OFF_PARENT  + 3*NN*4)              // u32 [3][NN] (sparse: only roots)
#define OFF_ROOTLIST (OFF_DENSE   + 3*NN*4)              // u32 [3][RCAP] (not zeroed)
#define OFF_COUNTS   (OFF_ROOTLIST+ 3*RCAP*4)            // i32 [3][BB][KMAX]   <- zeroed from here
#define OFF_ROOTLAB  (OFF_COUNTS  + 3*BB*KMAX*4)         // u32 [3][KMAX]
#define OFF_MMKEY    (OFF_ROOTLAB + 3*KMAX*4)            // u32 [3][BB][2] (~minkey,maxkey), both atomicMax
#define OFF_K        (OFF_MMKEY   + 3*BB*2*4)            // u32 [3] (+pad)
#define OFF_RCNT     (OFF_K       + 16)                  // u32 [3] (+pad)
#define OFF_BEST     (OFF_RCNT    + 16)                  // u32 [3][BB]
#define OFF_CENT     (OFF_BEST    + 3*BB*4)              // i32 [3][BB][3]
#define OFF_END      (OFF_CENT    + 3*BB*3*4)

// monotone float<->uint key (order-preserving incl. negatives)
__device__ __forceinline__ unsigned f2key(float f) {
    unsigned u = __float_as_uint(f);
    return (u & 0x80000000u) ? ~u : (u | 0x80000000u);
}
__device__ __forceinline__ float key2f(unsigned k) {
    unsigned u = (k & 0x80000000u) ? (k ^ 0x80000000u) : ~k;
    return __uint_as_float(u);
}

// ---- union-find, links always point to LARGER index => root = max linear idx ----
__device__ unsigned uf_find(unsigned* p, unsigned i) {
    while (true) {
        unsigned pi = ((volatile unsigned*)p)[i];
        if (pi == i) return i;
        unsigned gp = ((volatile unsigned*)p)[pi];
        if (gp != pi) ((volatile unsigned*)p)[i] = gp;  // path halving (monotone, safe)
        i = pi;
    }
}
__device__ void uf_union(unsigned* p, unsigned a, unsigned b) {
    while (true) {
        a = uf_find(p, a);
        b = uf_find(p, b);
        if (a == b) return;
        if (a < b) { unsigned t = a; a = b; b = t; }   // a = max root
        unsigned old = atomicCAS(&p[b], b, a);
        if (old == b) return;
        b = old;
    }
}

// ---- LDS union-find (same invariants, shared-memory atomics) ----
__device__ __forceinline__ unsigned lfind(unsigned* p, unsigned i) {
    while (true) {
        unsigned pi = ((volatile unsigned*)p)[i];
        if (pi == i) return i;
        unsigned gp = ((volatile unsigned*)p)[pi];
        if (gp != pi) ((volatile unsigned*)p)[i] = gp;
        i = pi;
    }
}
__device__ void lunion(unsigned* p, unsigned a, unsigned b) {
    while (true) {
        a = lfind(p, a);
        b = lfind(p, b);
        if (a == b) return;
        if (a < b) { unsigned t = a; a = b; b = t; }
        unsigned old = atomicCAS(&p[b], b, a);
        if (old == b) return;
        b = old;
    }
}

// channel mean + per-sample min/max, ONE z per dispatch (distinct kernel names
// in rocprof => downstream kernels stay visible in the top-5).
// Per-element summation tree identical to previous rounds (4 mod-4 c-class
// accumulators, combined ((a0+a1)+(a2+a3))/64) => bit-identical cmean.
template<int Z>
__global__ void k_cmean_z(const float* __restrict__ x, float* __restrict__ cmean,
                          unsigned* __restrict__ mmkey) {
    int b = blockIdx.y, t = threadIdx.x;
    int hw = blockIdx.x * 1024 + t * 4;
    const float* px = x + (size_t)b * CC * HWs + hw;
    float4 a0 = make_float4(0.f, 0.f, 0.f, 0.f), a1 = a0, a2 = a0, a3 = a0;
#pragma unroll
    for (int c = 0; c < CC; c += 4) {
        float4 v0 = *reinterpret_cast<const float4*>(px + (size_t)(c + 0) * HWs);
        float4 v1 = *reinterpret_cast<const float4*>(px + (size_t)(c + 1) * HWs);
        float4 v2 = *reinterpret_cast<const float4*>(px + (size_t)(c + 2) * HWs);
        float4 v3 = *reinterpret_cast<const float4*>(px + (size_t)(c + 3) * HWs);
        a0.x += v0.x; a0.y += v0.y; a0.z += v0.z; a0.w += v0.w;
        a1.x += v1.x; a1.y += v1.y; a1.z += v1.z; a1.w += v1.w;
        a2.x += v2.x; a2.y += v2.y; a2.z += v2.z; a2.w += v2.w;
        a3.x += v3.x; a3.y += v3.y; a3.z += v3.z; a3.w += v3.w;
    }
    const float inv = 1.f / 64.f;   // /64 exact pow2
    float4 s;
    s.x = ((a0.x + a1.x) + (a2.x + a3.x)) * inv;
    s.y = ((a0.y + a1.y) + (a2.y + a3.y)) * inv;
    s.z = ((a0.z + a1.z) + (a2.z + a3.z)) * inv;
    s.w = ((a0.w + a1.w) + (a2.w + a3.w)) * inv;
    float* cm = cmean + (size_t)Z * NN + (size_t)b * HWs + hw;
    *reinterpret_cast<float4*>(cm) = s;

    float mn = fminf(fminf(s.x, s.y), fminf(s.z, s.w));
    float mx = fmaxf(fmaxf(s.x, s.y), fmaxf(s.z, s.w));
    for (int o = 32; o; o >>= 1) {
        mn = fminf(mn, __shfl_down(mn, o));
        mx = fmaxf(mx, __shfl_down(mx, o));
    }
    __shared__ float smn[4], smx[4];
    int wid = t >> 6, lane = t & 63;
    if (lane == 0) { smn[wid] = mn; smx[wid] = mx; }
    __syncthreads();
    if (t == 0) {
        mn = fminf(fminf(smn[0], smn[1]), fminf(smn[2], smn[3]));
        mx = fmaxf(fmaxf(smx[0], smx[1]), fmaxf(smx[2], smx[3]));
        atomicMax(&mmkey[(Z * BB + b) * 2 + 0], ~f2key(mn));
        atomicMax(&mmkey[(Z * BB + b) * 2 + 1], f2key(mx));
    }
}

// fused: normalize -> mask -> LOCAL run-based CCL over a [16b x 8h x 32w] tile.
// 512 threads (8 phases). Also emits a compacted global list of tile-root
// voxel indices so the downstream compress pass touches only roots, not NN.
__global__ void __launch_bounds__(TPB) k_mask_ccl(const float* __restrict__ cmean,
                                                  const unsigned* __restrict__ mmkey,
                                                  unsigned* __restrict__ parent_all,
                                                  unsigned* __restrict__ rootlist,
                                                  unsigned* __restrict__ rootcnt) {
    int z = blockIdx.z;
    int h0 = blockIdx.y * TILE_H;
    int w0 = blockIdx.x * TILE_W;
    int t = threadIdx.x;
    int lane = t & 63;
    __shared__ unsigned sp[TVOX];
    __shared__ unsigned rowmask[NROWS];
    __shared__ float smn[BB], smx[BB];
    __shared__ unsigned lcnt, sbase;
    if (t == 0) lcnt = 0;
    if (t < BB) {
        smn[t] = key2f(~mmkey[(z * BB + t) * 2 + 0]);
        smx[t] = key2f(mmkey[(z * BB + t) * 2 + 1]);
    }
    __syncthreads();
#pragma unroll
    for (int ph = 0; ph < TVOX / TPB; ph++) {
        int li = ph * TPB + t;
        int lb = li >> 8, lh = (li >> 5) & 7, lw = li & 31;
        unsigned gi = lb * HWs + (h0 + lh) * WW + (w0 + lw);
        float c = cmean[(size_t)z * NN + gi];
        bool mkd = (c - smn[lb]) / (smx[lb] - smn[lb]) >= 0.4f;
        unsigned long long bal = __ballot(mkd);
        unsigned m = (lane < 32) ? (unsigned)bal : (unsigned)(bal >> 32);
        int row = li >> 5;
        if ((lane & 31) == 0) rowmask[row] = m;
        unsigned v = INV;
        if (mkd) {
            int j = __ffsll(~((unsigned long long)m >> lw)) - 1;  // trailing-ones >=1
            v = (unsigned)((row << 5) + lw + j - 1);              // run root (run max)
        }
        sp[li] = v;
    }
    __syncthreads();
#pragma unroll
    for (int ph = 0; ph < TVOX / TPB; ph++) {
        int li = ph * TPB + t;
        int row = li >> 5, lw = li & 31;
        unsigned m = rowmask[row];
        if (!((m >> lw) & 1)) continue;
        int lh = row & 7;
        if (lh < TILE_H - 1) {                       // h-edge, row -> row+1
            unsigned m2 = rowmask[row + 1];
            unsigned ov = m & m2;
            bool leader = ((ov >> lw) & 1) && (lw == 0 || !((ov >> (lw - 1)) & 1));
            if (leader) {
                int j2 = __ffsll(~((unsigned long long)m2 >> lw)) - 1;
                lunion(sp, sp[li], (unsigned)(((row + 1) << 5) + lw + j2 - 1));
            }
        }
        if (row < NROWS - 8) {                       // b-edge, row -> row+8
            unsigned m2 = rowmask[row + 8];
            unsigned ov = m & m2;
            bool leader = ((ov >> lw) & 1) && (lw == 0 || !((ov >> (lw - 1)) & 1));
            if (leader) {
                int j2 = __ffsll(~((unsigned long long)m2 >> lw)) - 1;
                lunion(sp, sp[li], (unsigned)(((row + 8) << 5) + lw + j2 - 1));
            }
        }
    }
    __syncthreads();
    // pointer-jump flatten: tree static now; races only move entries rootward
#pragma unroll
    for (int it = 0; it < 4; it++) {
#pragma unroll
        for (int ph = 0; ph < TVOX / TPB; ph++) {
            int li = ph * TPB + t;
            unsigned v = sp[li];
            if (v != INV) {
                unsigned w = sp[v];
                if (w != v) sp[li] = w;
            }
        }
    }
    __syncthreads();
    unsigned myroot[TVOX / TPB];
    unsigned myoff[TVOX / TPB];
    int nmy = 0;
#pragma unroll
    for (int ph = 0; ph < TVOX / TPB; ph++) {
        int li = ph * TPB + t;
        int lb = li >> 8, lh = (li >> 5) & 7, lw = li & 31;
        unsigned gi = lb * HWs + (h0 + lh) * WW + (w0 + lw);
        unsigned v = sp[li];
        if (v != INV) {
            unsigned r = v;
            while (sp[r] != r) r = sp[r];           // short after flatten
            int rb = r >> 8, rh = (r >> 5) & 7, rw = r & 31;
            v = rb * HWs + (h0 + rh) * WW + (w0 + rw);
            if (r == (unsigned)li) {                // tile root -> record
                myroot[nmy] = gi;
                myoff[nmy] = atomicAdd(&lcnt, 1u);
                nmy++;
            }
        }
        parent_all[(size_t)z * NN + gi] = v;
    }
    __syncthreads();
    if (t == 0) sbase = atomicAdd(&rootcnt[z], lcnt);
    __syncthreads();
    for (int k = 0; k < nmy; k++) {
        unsigned idx = sbase + myoff[k];
        if (idx < RCAP) rootlist[(size_t)z * RCAP + idx] = myroot[k];
    }
}

// wave-level dedup'd union: one uf_union per DISTINCT (root,root) pair per wave
// call. All 64 lanes must be active (callers guarantee wave-uniform control).
__device__ __forceinline__ void wave_union(unsigned* p, unsigned pi, unsigned pj, int lane) {
    bool valid = (pi != INV) && (pj != INV) && (pi != pj);
    unsigned lo = pi < pj ? pi : pj;
    unsigned hi = pi < pj ? pj : pi;
    unsigned long long key = valid ? (((unsigned long long)hi << 32) | lo) : ~0ull;
    unsigned long long rem = __ballot(valid);
    while (rem) {
        int leader = __ffsll((long long)rem) - 1;
        unsigned long long lkey = __shfl(key, leader);
        unsigned long long m = __ballot(valid && key == lkey) & rem;
        if (lane == leader) uf_union(p, pi, pj);
        rem &= ~m;
    }
}

// cross-tile merge, ONE WAVE PER TILE-PAIR BOUNDARY.
// Replaces the per-edge-thread k_merge_bnd whose ~5-10k contended unions across
// 888 blocks / 8 XCDs cost 80us in CAS+coherence serialization (hbm 2.4%,
// VALU 0.7% => pure latency stall). p[i] is already the tile-root handle after
// k_mask_ccl, so each wave loads its boundary cells' (p[i],p[j]) and issues
// ~1 union per distinct component pair. Same edge coverage as before.
__global__ void k_merge_tp(unsigned* __restrict__ parent_all) {
    int z = blockIdx.y;
    unsigned* p = parent_all + (size_t)z * NN;
    int pair = blockIdx.x * 4 + (threadIdx.x >> 6);   // wave-uniform
    if (pair >= NPAIR) return;
    int lane = threadIdx.x & 63;
    if (pair < NPW) {
        // w-boundary: column w = wb*32+31, tile-row ht; cells = 16b x 8h = 128
        int wb = pair / 16, ht = pair % 16;
        int w = wb * TILE_W + (TILE_W - 1);
#pragma unroll
        for (int r = 0; r < 2; r++) {
            int c = r * 64 + lane;
            int b = c >> 3, lh = c & 7;
            unsigned i = b * HWs + (ht * TILE_H + lh) * WW + w;
            wave_union(p, p[i], p[i + 1], lane);
        }
    } else {
        // h-boundary: row h = hb*8+7, tile-col wt; cells = 16b x 32w = 512
        int e = pair - NPW;
        int hb = e / 8, wt = e % 8;
        int h = hb * TILE_H + (TILE_H - 1);
#pragma unroll
        for (int r = 0; r < 8; r++) {
            int c = r * 64 + lane;
            int b = c >> 5, lw = c & 31;
            unsigned i = b * HWs + h * WW + wt * TILE_W + lw;
            wave_union(p, p[i], p[i + WW], lane);
        }
    }
}

// compress ONLY tile roots (p[t] -> global root) + dense-id the global roots.
// After this, root(voxel i) == p[p[i]] exactly, with no NN-wide write pass.
__global__ void k_rootcompress(unsigned* __restrict__ parent_all,
                               const unsigned* __restrict__ rootlist,
                               const unsigned* __restrict__ rootcnt,
                               unsigned* __restrict__ dense_all,
                               unsigned* __restrict__ rootlab, unsigned* __restrict__ Kc) {
    int z = blockIdx.y;
    unsigned* p = parent_all + (size_t)z * NN;
    unsigned cnt = rootcnt[z]; if (cnt > RCAP) cnt = RCAP;
    for (unsigned j = blockIdx.x * 256 + threadIdx.x; j < cnt; j += gridDim.x * 256) {
        unsigned r = rootlist[(size_t)z * RCAP + j];
        unsigned g = uf_find(p, r);
        p[r] = g;
        if (g == r) {
            unsigned id = atomicAdd(&Kc[z], 1u);
            if (id >= KMAX) id = KMAX - 1;   // never expected
            dense_all[(size_t)z * NN + g] = id;
            rootlab[z * KMAX + id] = g;
        }
    }
}

// per-slice per-component counts, wave-aggregated atomics; root = p[p[i]]
__global__ void k_count(const unsigned* __restrict__ parent_all,
                        const unsigned* __restrict__ dense_all, int* __restrict__ counts) {
    int z = blockIdx.y;
    const unsigned* p = parent_all + (size_t)z * NN;
    const unsigned* d = dense_all + (size_t)z * NN;
    int i = blockIdx.x * 256 + threadIdx.x;
    int b = i >> 15;   // uniform across the wave (64 | HWs)
    unsigned pi = p[i];
    bool valid = (pi != INV);
    int id = valid ? (int)d[p[pi]] : -1;
    int lane = threadIdx.x & 63;
    int* crow = counts + ((size_t)z * BB + b) * KMAX;
    unsigned long long rem = __ballot(valid);
    while (rem) {
        int leader = __ffsll(rem) - 1;
        int lid = __shfl(id, leader);
        unsigned long long m = __ballot(valid && id == lid) & rem;
        if (lane == leader) atomicAdd(&crow[lid], (int)__popcll(m));
        rem &= ~m;
    }
}

// per-slice argmax: max count, tie -> smallest root label (== reference argmax semantics)
__global__ void k_best(const int* __restrict__ counts, const unsigned* __restrict__ rootlab,
                       const unsigned* __restrict__ Kc, unsigned* __restrict__ best) {
    int z = blockIdx.y, b = blockIdx.x, t = threadIdx.x;
    const int* crow = counts + ((size_t)z * BB + b) * KMAX;
    const unsigned* rl = rootlab + z * KMAX;
    unsigned K = Kc[z]; if (K > KMAX) K = KMAX;
    int bc = -1; unsigned brl = INV; int bj = 0;
    for (unsigned j = t; j < K; j += blockDim.x) {
        int c = crow[j]; unsigned r = rl[j];
        if (c > bc || (c == bc && r < brl)) { bc = c; brl = r; bj = (int)j; }
    }
    __shared__ int sc[256]; __shared__ unsigned sr[256]; __shared__ int sj[256];
    sc[t] = bc; sr[t] = brl; sj[t] = bj;
    __syncthreads();
    for (int o = 128; o; o >>= 1) {
        if (t < o) {
            int c2 = sc[t + o]; unsigned r2 = sr[t + o];
            if (c2 > sc[t] || (c2 == sc[t] && r2 < sr[t])) { sc[t] = c2; sr[t] = r2; sj[t] = sj[t + o]; }
        }
        __syncthreads();
    }
    if (t == 0) best[z * BB + b] = (unsigned)sj[0];
}

// masked normalized output + integer centroid sums; root = p[p[i]]
__global__ void k_result(const float* __restrict__ cmean, const unsigned* __restrict__ parent_all,
                         const unsigned* __restrict__ dense_all, const unsigned* __restrict__ mmkey,
                         const unsigned* __restrict__ best, float* __restrict__ out,
                         int* __restrict__ cent) {
    int z = blockIdx.y;
    int i = blockIdx.x * 256 + threadIdx.x;
    int b = i >> 15;
    const unsigned* p = parent_all + (size_t)z * NN;
    unsigned pi = p[i];
    bool big = false;
    if (pi != INV) big = (dense_all[(size_t)z * NN + p[pi]] == best[z * BB + b]);
    float mn = key2f(~mmkey[(z * BB + b) * 2 + 0]);
    float mx = key2f(mmkey[(z * BB + b) * 2 + 1]);
    float c = cmean[(size_t)z * NN + i];
    float v = (c - mn) / (mx - mn);
    out[32 + (size_t)z * NN + i] = big ? v : 0.f;

    int c1 = big ? 1 : 0;
    int ch = big ? ((i >> 8) & (HH - 1)) : 0;
    int cw = big ? (i & (WW - 1)) : 0;
    for (int o = 32; o; o >>= 1) {
        c1 += __shfl_down(c1, o); ch += __shfl_down(ch, o); cw += __shfl_down(cw, o);
    }
    __shared__ int s0[4], s1[4], s2[4];
    int wid = threadIdx.x >> 6, lane = threadIdx.x & 63;
    if (lane == 0) { s0[wid] = c1; s1[wid] = ch; s2[wid] = cw; }
    __syncthreads();
    if (threadIdx.x == 0) {
        c1 = s0[0] + s0[1] + s0[2] + s0[3];
        ch = s1[0] + s1[1] + s1[2] + s1[3];
        cw = s2[0] + s2[1] + s2[2] + s2[3];
        int* ct = cent + (z * BB + b) * 3;
        atomicAdd(&ct[0], c1); atomicAdd(&ct[1], ch); atomicAdd(&ct[2], cw);
    }
}

__global__ void k_final(const int* __restrict__ cent, float* __restrict__ out) {
    int b = threadIdx.x;
    if (b >= BB) return;
    const float PI = (float)M_PI;  // f32(np.pi)
    float th[3], ph[3];
    for (int z = 0; z < 3; z++) {
        const int* ct = cent + (z * BB + b) * 3;
        float cnt = (float)ct[0];
        float hm = (float)ct[1] / cnt;   // integer sums exact in f32 (< 2^24)
        float wm = (float)ct[2] / cnt;
        ph[z] = (0.5f - hm / (float)HH) * PI;
        th[z] = (wm / (float)WW - 0.5f) * 2.0f * PI;
    }
    auto dist = [PI](float t1, float p1, float t2, float p2) {
        float cosd = sinf(t1) * sinf(t2) + cosf(t1) * cosf(t2) * cosf(p1 - p2);
        float d = acosf(cosd);
        if (isnan(d)) d = 0.f;           // jnp.nan_to_num semantics
        return d / PI;
    };
    out[b]      = dist(th[0], ph[0], th[1], ph[1]);
    out[BB + b] = dist(th[1], ph[1], th[2], ph[2]);
}

extern "C" void kernel_launch(void* const* d_in, const int* in_sizes, int n_in,
                              void* d_out, int out_size, void* d_ws, size_t ws_size,
                              hipStream_t stream) {
    const float* x0 = (const float*)d_in[0];
    const float* x1 = (const float*)d_in[1];
    const float* x2 = (const float*)d_in[2];
    float* out = (float*)d_out;
    char* ws = (char*)d_ws;
    float*    cmean    = (float*)(ws + OFF_CMEAN);
    unsigned* parent   = (unsigned*)(ws + OFF_PARENT);
    unsigned* dense    = (unsigned*)(ws + OFF_DENSE);
    unsigned* rootlist = (unsigned*)(ws + OFF_ROOTLIST);
    int*      counts   = (int*)(ws + OFF_COUNTS);
    unsigned* rootlab  = (unsigned*)(ws + OFF_ROOTLAB);
    unsigned* mmkey    = (unsigned*)(ws + OFF_MMKEY);
    unsigned* Kc       = (unsigned*)(ws + OFF_K);
    unsigned* rootcnt  = (unsigned*)(ws + OFF_RCNT);
    unsigned* best     = (unsigned*)(ws + OFF_BEST);
    int*      cent     = (int*)(ws + OFF_CENT);

    hipMemsetAsync(ws + OFF_COUNTS, 0, OFF_END - OFF_COUNTS, stream);
    hipLaunchKernelGGL(k_cmean_z<0>, dim3(HWs / 1024, BB), dim3(256), 0, stream, x0, cmean, mmkey);
    hipLaunchKernelGGL(k_cmean_z<1>, dim3(HWs / 1024, BB), dim3(256), 0, stream, x1, cmean, mmkey);
    hipLaunchKernelGGL(k_cmean_z<2>, dim3(HWs / 1024, BB), dim3(256), 0, stream, x2, cmean, mmkey);
    hipLaunchKernelGGL(k_mask_ccl, dim3(WW / TILE_W, HH / TILE_H, 3), dim3(TPB), 0, stream,
                       cmean, mmkey, parent, rootlist, rootcnt);
    hipLaunchKernelGGL(k_merge_tp, dim3((NPAIR + 3) / 4, 3), dim3(256), 0, stream, parent);
    hipLaunchKernelGGL(k_rootcompress, dim3(32, 3), dim3(256), 0, stream,
                       parent, rootlist, rootcnt, dense, rootlab, Kc);
    hipLaunchKernelGGL(k_count, dim3(NN / 256, 3), dim3(256), 0, stream, parent, dense, counts);
    hipLaunchKernelGGL(k_best, dim3(BB, 3), dim3(256), 0, stream, counts, rootlab, Kc, best);
    hipLaunchKernelGGL(k_result, dim3(NN / 256, 3), dim3(256), 0, stream,
                       cmean, parent, dense, mmkey, best, out, cent);
    hipLaunchKernelGGL(k_final, dim3(1), dim3(64), 0, stream, cent, out);
}

// Round 6
// 492.617 us; speedup vs baseline: 1.1964x; 1.0763x over previous
//
#include <hip/hip_runtime.h>
#include <math.h>

#define BB 16
#define CC 64
#define HH 128
#define WW 256
#define HWs 32768      // HH*WW
#define NN 524288      // BB*HH*WW
#define KMAX 8192
#define RCAP 65536     // tile-root list capacity per z
#define INV 0xFFFFFFFFu
#define INV16 0xFFFFu

// tile: full batch depth x 8h x 32w = 4096 voxels, 512 threads
#define TILE_H 8
#define TILE_W 32
#define TVOX 4096
#define TPB 512
#define NROWS 128      // BB * TILE_H rows of 32 w-bits

// tile-pair boundaries (for the wave-per-pair merge)
#define NPW 112        // 7 internal w-boundaries * 16 h-tiles
#define NPH 120        // 15 internal h-boundaries * 8 w-tiles
#define NPAIR 232

// ---- workspace layout (bytes) ----
#define OFF_CMEAN    0                                   // f32 [3][NN]
#define OFF_PARENT   (OFF_CMEAN   + 3*NN*4)              // u32 [3][NN]
#define OFF_DENSE    (OFF_PARENT  + 3*NN*4)              // u32 [3][NN] (sparse: only roots)
#define OFF_ROOTLIST (OFF_DENSE   + 3*NN*4)              // u32 [3][RCAP] (not zeroed)
#define OFF_COUNTS   (OFF_ROOTLIST+ 3*RCAP*4)            // i32 [3][BB][KMAX]   <- zeroed from here
#define OFF_ROOTLAB  (OFF_COUNTS  + 3*BB*KMAX*4)         // u32 [3][KMAX]
#define OFF_MMKEY    (OFF_ROOTLAB + 3*KMAX*4)            // u32 [3][BB][2] (~minkey,maxkey), both atomicMax
#define OFF_K        (OFF_MMKEY   + 3*BB*2*4)            // u32 [3] (+pad)
#define OFF_RCNT     (OFF_K       + 16)                  // u32 [3] (+pad)
#define OFF_BEST     (OFF_RCNT    + 16)                  // u32 [3][BB]
#define OFF_CENT     (OFF_BEST    + 3*BB*4)              // i32 [3][BB][3]
#define OFF_END      (OFF_CENT    + 3*BB*3*4)
#define OFF_IDC      OFF_END                             // u16 [3][NN] per-voxel dense id (fully overwritten)

// monotone float<->uint key (order-preserving incl. negatives)
__device__ __forceinline__ unsigned f2key(float f) {
    unsigned u = __float_as_uint(f);
    return (u & 0x80000000u) ? ~u : (u | 0x80000000u);
}
__device__ __forceinline__ float key2f(unsigned k) {
    unsigned u = (k & 0x80000000u) ? (k ^ 0x80000000u) : ~k;
    return __uint_as_float(u);
}

// ---- union-find, links always point to LARGER index => root = max linear idx ----
__device__ unsigned uf_find(unsigned* p, unsigned i) {
    while (true) {
        unsigned pi = ((volatile unsigned*)p)[i];
        if (pi == i) return i;
        unsigned gp = ((volatile unsigned*)p)[pi];
        if (gp != pi) ((volatile unsigned*)p)[i] = gp;  // path halving (monotone, safe)
        i = pi;
    }
}
__device__ void uf_union(unsigned* p, unsigned a, unsigned b) {
    while (true) {
        a = uf_find(p, a);
        b = uf_find(p, b);
        if (a == b) return;
        if (a < b) { unsigned t = a; a = b; b = t; }   // a = max root
        unsigned old = atomicCAS(&p[b], b, a);
        if (old == b) return;
        b = old;
    }
}

// ---- LDS union-find (same invariants, shared-memory atomics) ----
__device__ __forceinline__ unsigned lfind(unsigned* p, unsigned i) {
    while (true) {
        unsigned pi = ((volatile unsigned*)p)[i];
        if (pi == i) return i;
        unsigned gp = ((volatile unsigned*)p)[pi];
        if (gp != pi) ((volatile unsigned*)p)[i] = gp;
        i = pi;
    }
}
__device__ void lunion(unsigned* p, unsigned a, unsigned b) {
    while (true) {
        a = lfind(p, a);
        b = lfind(p, b);
        if (a == b) return;
        if (a < b) { unsigned t = a; a = b; b = t; }
        unsigned old = atomicCAS(&p[b], b, a);
        if (old == b) return;
        b = old;
    }
}

// wave-level dedup'd union: one uf_union per DISTINCT (root,root) pair per call.
// All 64 lanes of the wave must enter together.
__device__ __forceinline__ void wave_union(unsigned* p, unsigned pi, unsigned pj, int lane) {
    bool valid = (pi != INV) && (pj != INV) && (pi != pj);
    unsigned lo = pi < pj ? pi : pj;
    unsigned hi = pi < pj ? pj : pi;
    unsigned long long key = valid ? (((unsigned long long)hi << 32) | lo) : ~0ull;
    unsigned long long rem = __ballot(valid);
    while (rem) {
        int leader = __ffsll((long long)rem) - 1;
        unsigned long long lkey = __shfl(key, leader);
        unsigned long long m = __ballot(valid && key == lkey) & rem;
        if (lane == leader) uf_union(p, pi, pj);
        rem &= ~m;
    }
}

// channel mean + per-sample min/max, ONE z per dispatch. Per-element summation
// tree identical to previous rounds (4 mod-4 c-class accumulators,
// ((a0+a1)+(a2+a3))/64) => bit-identical cmean.
template<int Z>
__global__ void k_cmean_z(const float* __restrict__ x, float* __restrict__ cmean,
                          unsigned* __restrict__ mmkey) {
    int b = blockIdx.y, t = threadIdx.x;
    int hw = blockIdx.x * 1024 + t * 4;
    const float* px = x + (size_t)b * CC * HWs + hw;
    float4 a0 = make_float4(0.f, 0.f, 0.f, 0.f), a1 = a0, a2 = a0, a3 = a0;
#pragma unroll
    for (int c = 0; c < CC; c += 4) {
        float4 v0 = *reinterpret_cast<const float4*>(px + (size_t)(c + 0) * HWs);
        float4 v1 = *reinterpret_cast<const float4*>(px + (size_t)(c + 1) * HWs);
        float4 v2 = *reinterpret_cast<const float4*>(px + (size_t)(c + 2) * HWs);
        float4 v3 = *reinterpret_cast<const float4*>(px + (size_t)(c + 3) * HWs);
        a0.x += v0.x; a0.y += v0.y; a0.z += v0.z; a0.w += v0.w;
        a1.x += v1.x; a1.y += v1.y; a1.z += v1.z; a1.w += v1.w;
        a2.x += v2.x; a2.y += v2.y; a2.z += v2.z; a2.w += v2.w;
        a3.x += v3.x; a3.y += v3.y; a3.z += v3.z; a3.w += v3.w;
    }
    const float inv = 1.f / 64.f;   // /64 exact pow2
    float4 s;
    s.x = ((a0.x + a1.x) + (a2.x + a3.x)) * inv;
    s.y = ((a0.y + a1.y) + (a2.y + a3.y)) * inv;
    s.z = ((a0.z + a1.z) + (a2.z + a3.z)) * inv;
    s.w = ((a0.w + a1.w) + (a2.w + a3.w)) * inv;
    float* cm = cmean + (size_t)Z * NN + (size_t)b * HWs + hw;
    *reinterpret_cast<float4*>(cm) = s;

    float mn = fminf(fminf(s.x, s.y), fminf(s.z, s.w));
    float mx = fmaxf(fmaxf(s.x, s.y), fmaxf(s.z, s.w));
    for (int o = 32; o; o >>= 1) {
        mn = fminf(mn, __shfl_down(mn, o));
        mx = fmaxf(mx, __shfl_down(mx, o));
    }
    __shared__ float smn[4], smx[4];
    int wid = t >> 6, lane = t & 63;
    if (lane == 0) { smn[wid] = mn; smx[wid] = mx; }
    __syncthreads();
    if (t == 0) {
        mn = fminf(fminf(smn[0], smn[1]), fminf(smn[2], smn[3]));
        mx = fmaxf(fmaxf(smx[0], smx[1]), fmaxf(smx[2], smx[3]));
        atomicMax(&mmkey[(Z * BB + b) * 2 + 0], ~f2key(mn));
        atomicMax(&mmkey[(Z * BB + b) * 2 + 1], f2key(mx));
    }
}

// fused: normalize -> mask -> LOCAL run-based CCL over a [16b x 8h x 32w] tile.
// 512 threads (8 phases). Also emits a compacted global list of tile-root
// voxel indices so the downstream compress pass touches only roots, not NN.
__global__ void __launch_bounds__(TPB) k_mask_ccl(const float* __restrict__ cmean,
                                                  const unsigned* __restrict__ mmkey,
                                                  unsigned* __restrict__ parent_all,
                                                  unsigned* __restrict__ rootlist,
                                                  unsigned* __restrict__ rootcnt) {
    int z = blockIdx.z;
    int h0 = blockIdx.y * TILE_H;
    int w0 = blockIdx.x * TILE_W;
    int t = threadIdx.x;
    int lane = t & 63;
    __shared__ unsigned sp[TVOX];
    __shared__ unsigned rowmask[NROWS];
    __shared__ float smn[BB], smx[BB];
    __shared__ unsigned lcnt, sbase;
    if (t == 0) lcnt = 0;
    if (t < BB) {
        smn[t] = key2f(~mmkey[(z * BB + t) * 2 + 0]);
        smx[t] = key2f(mmkey[(z * BB + t) * 2 + 1]);
    }
    __syncthreads();
#pragma unroll
    for (int ph = 0; ph < TVOX / TPB; ph++) {
        int li = ph * TPB + t;
        int lb = li >> 8, lh = (li >> 5) & 7, lw = li & 31;
        unsigned gi = lb * HWs + (h0 + lh) * WW + (w0 + lw);
        float c = cmean[(size_t)z * NN + gi];
        bool mkd = (c - smn[lb]) / (smx[lb] - smn[lb]) >= 0.4f;
        unsigned long long bal = __ballot(mkd);
        unsigned m = (lane < 32) ? (unsigned)bal : (unsigned)(bal >> 32);
        int row = li >> 5;
        if ((lane & 31) == 0) rowmask[row] = m;
        unsigned v = INV;
        if (mkd) {
            int j = __ffsll(~((unsigned long long)m >> lw)) - 1;  // trailing-ones >=1
            v = (unsigned)((row << 5) + lw + j - 1);              // run root (run max)
        }
        sp[li] = v;
    }
    __syncthreads();
#pragma unroll
    for (int ph = 0; ph < TVOX / TPB; ph++) {
        int li = ph * TPB + t;
        int row = li >> 5, lw = li & 31;
        unsigned m = rowmask[row];
        if (!((m >> lw) & 1)) continue;
        int lh = row & 7;
        if (lh < TILE_H - 1) {                       // h-edge, row -> row+1
            unsigned m2 = rowmask[row + 1];
            unsigned ov = m & m2;
            bool leader = ((ov >> lw) & 1) && (lw == 0 || !((ov >> (lw - 1)) & 1));
            if (leader) {
                int j2 = __ffsll(~((unsigned long long)m2 >> lw)) - 1;
                lunion(sp, sp[li], (unsigned)(((row + 1) << 5) + lw + j2 - 1));
            }
        }
        if (row < NROWS - 8) {                       // b-edge, row -> row+8
            unsigned m2 = rowmask[row + 8];
            unsigned ov = m & m2;
            bool leader = ((ov >> lw) & 1) && (lw == 0 || !((ov >> (lw - 1)) & 1));
            if (leader) {
                int j2 = __ffsll(~((unsigned long long)m2 >> lw)) - 1;
                lunion(sp, sp[li], (unsigned)(((row + 8) << 5) + lw + j2 - 1));
            }
        }
    }
    __syncthreads();
    // pointer-jump flatten: tree static now; races only move entries rootward
#pragma unroll
    for (int it = 0; it < 4; it++) {
#pragma unroll
        for (int ph = 0; ph < TVOX / TPB; ph++) {
            int li = ph * TPB + t;
            unsigned v = sp[li];
            if (v != INV) {
                unsigned w = sp[v];
                if (w != v) sp[li] = w;
            }
        }
    }
    __syncthreads();
    unsigned myroot[TVOX / TPB];
    unsigned myoff[TVOX / TPB];
    int nmy = 0;
#pragma unroll
    for (int ph = 0; ph < TVOX / TPB; ph++) {
        int li = ph * TPB + t;
        int lb = li >> 8, lh = (li >> 5) & 7, lw = li & 31;
        unsigned gi = lb * HWs + (h0 + lh) * WW + (w0 + lw);
        unsigned v = sp[li];
        if (v != INV) {
            unsigned r = v;
            while (sp[r] != r) r = sp[r];           // short after flatten
            int rb = r >> 8, rh = (r >> 5) & 7, rw = r & 31;
            v = rb * HWs + (h0 + rh) * WW + (w0 + rw);
            if (r == (unsigned)li) {                // tile root -> record
                myroot[nmy] = gi;
                myoff[nmy] = atomicAdd(&lcnt, 1u);
                nmy++;
            }
        }
        parent_all[(size_t)z * NN + gi] = v;
    }
    __syncthreads();
    if (t == 0) sbase = atomicAdd(&rootcnt[z], lcnt);
    __syncthreads();
    for (int k = 0; k < nmy; k++) {
        unsigned idx = sbase + myoff[k];
        if (idx < RCAP) rootlist[(size_t)z * RCAP + idx] = myroot[k];
    }
}

// cross-tile merge, ONE WAVE PER TILE-PAIR BOUNDARY (verified round 4: removed
// the 80us CAS/coherence stall of the per-edge version).
__global__ void k_merge_tp(unsigned* __restrict__ parent_all) {
    int z = blockIdx.y;
    unsigned* p = parent_all + (size_t)z * NN;
    int pair = blockIdx.x * 4 + (threadIdx.x >> 6);   // wave-uniform
    if (pair >= NPAIR) return;
    int lane = threadIdx.x & 63;
    if (pair < NPW) {
        // w-boundary: column w = wb*32+31, tile-row ht; cells = 16b x 8h = 128
        int wb = pair / 16, ht = pair % 16;
        int w = wb * TILE_W + (TILE_W - 1);
#pragma unroll
        for (int r = 0; r < 2; r++) {
            int c = r * 64 + lane;
            int b = c >> 3, lh = c & 7;
            unsigned i = b * HWs + (ht * TILE_H + lh) * WW + w;
            wave_union(p, p[i], p[i + 1], lane);
        }
    } else {
        // h-boundary: row h = hb*8+7, tile-col wt; cells = 16b x 32w = 512
        int e = pair - NPW;
        int hb = e / 8, wt = e % 8;
        int h = hb * TILE_H + (TILE_H - 1);
#pragma unroll
        for (int r = 0; r < 8; r++) {
            int c = r * 64 + lane;
            int b = c >> 5, lw = c & 31;
            unsigned i = b * HWs + h * WW + wt * TILE_W + lw;
            wave_union(p, p[i], p[i + WW], lane);
        }
    }
}

// compress ONLY tile roots (p[t] -> global root) + dense-id the global roots.
// After this, root(voxel i) == p[p[i]] exactly, with no NN-wide write pass.
__global__ void k_rootcompress(unsigned* __restrict__ parent_all,
                               const unsigned* __restrict__ rootlist,
                               const unsigned* __restrict__ rootcnt,
                               unsigned* __restrict__ dense_all,
                               unsigned* __restrict__ rootlab, unsigned* __restrict__ Kc) {
    int z = blockIdx.y;
    unsigned* p = parent_all + (size_t)z * NN;
    unsigned cnt = rootcnt[z]; if (cnt > RCAP) cnt = RCAP;
    for (unsigned j = blockIdx.x * 256 + threadIdx.x; j < cnt; j += gridDim.x * 256) {
        unsigned r = rootlist[(size_t)z * RCAP + j];
        unsigned g = uf_find(p, r);
        p[r] = g;
        if (g == r) {
            unsigned id = atomicAdd(&Kc[z], 1u);
            if (id >= KMAX) id = KMAX - 1;   // never expected
            dense_all[(size_t)z * NN + g] = id;
            rootlab[z * KMAX + id] = g;
        }
    }
}

// per-slice per-component counts + CACHE the resolved per-voxel dense id into
// idc (u16), so k_result is a pure streaming pass with no dependent gathers.
// 2 voxels/thread, vectorized parent load. root = p[p[i]].
__global__ void k_count(const unsigned* __restrict__ parent_all,
                        const unsigned* __restrict__ dense_all, int* __restrict__ counts,
                        unsigned short* __restrict__ idc) {
    int z = blockIdx.y;
    const unsigned* p = parent_all + (size_t)z * NN;
    const unsigned* d = dense_all + (size_t)z * NN;
    unsigned i0 = (blockIdx.x * 256u + threadIdx.x) * 2u;
    int b = i0 >> 15;   // uniform across the wave (128 consecutive voxels/wave)
    uint2 pp = *reinterpret_cast<const uint2*>(p + i0);
    unsigned id0 = INV16, id1 = INV16;
    if (pp.x != INV) id0 = d[p[pp.x]];
    if (pp.y != INV) id1 = d[p[pp.y]];
    *reinterpret_cast<ushort2*>(idc + (size_t)z * NN + i0) =
        make_ushort2((unsigned short)id0, (unsigned short)id1);
    int lane = threadIdx.x & 63;
    int* crow = counts + ((size_t)z * BB + b) * KMAX;
#pragma unroll
    for (int q = 0; q < 2; q++) {
        unsigned idq = q ? id1 : id0;
        bool valid = idq != INV16;
        unsigned long long rem = __ballot(valid);
        while (rem) {
            int leader = __ffsll((long long)rem) - 1;
            unsigned lid = __shfl(idq, leader);
            unsigned long long m = __ballot(valid && idq == lid) & rem;
            if (lane == leader) atomicAdd(&crow[lid], (int)__popcll(m));
            rem &= ~m;
        }
    }
}

// per-slice argmax: max count, tie -> smallest root label (== reference argmax semantics)
__global__ void k_best(const int* __restrict__ counts, const unsigned* __restrict__ rootlab,
                       const unsigned* __restrict__ Kc, unsigned* __restrict__ best) {
    int z = blockIdx.y, b = blockIdx.x, t = threadIdx.x;
    const int* crow = counts + ((size_t)z * BB + b) * KMAX;
    const unsigned* rl = rootlab + z * KMAX;
    unsigned K = Kc[z]; if (K > KMAX) K = KMAX;
    int bc = -1; unsigned brl = INV; int bj = 0;
    for (unsigned j = t; j < K; j += blockDim.x) {
        int c = crow[j]; unsigned r = rl[j];
        if (c > bc || (c == bc && r < brl)) { bc = c; brl = r; bj = (int)j; }
    }
    __shared__ int sc[256]; __shared__ unsigned sr[256]; __shared__ int sj[256];
    sc[t] = bc; sr[t] = brl; sj[t] = bj;
    __syncthreads();
    for (int o = 128; o; o >>= 1) {
        if (t < o) {
            int c2 = sc[t + o]; unsigned r2 = sr[t + o];
            if (c2 > sc[t] || (c2 == sc[t] && r2 < sr[t])) { sc[t] = c2; sr[t] = r2; sj[t] = sj[t + o]; }
        }
        __syncthreads();
    }
    if (t == 0) best[z * BB + b] = (unsigned)sj[0];
}

// masked normalized output + integer centroid sums — PURE STREAMING now:
// reads idc (u16x2) + cmean (f32x2), writes out (f32x2). No gathers.
__global__ void k_result(const float* __restrict__ cmean, const unsigned short* __restrict__ idc,
                         const unsigned* __restrict__ mmkey, const unsigned* __restrict__ best,
                         float* __restrict__ out, int* __restrict__ cent) {
    int z = blockIdx.y;
    unsigned i0 = (blockIdx.x * 256u + threadIdx.x) * 2u;
    int b = i0 >> 15;   // uniform per block (512 consecutive voxels)
    float mn = key2f(~mmkey[(z * BB + b) * 2 + 0]);
    float mx = key2f(mmkey[(z * BB + b) * 2 + 1]);
    unsigned short bst = (unsigned short)best[z * BB + b];
    ushort2 id2 = *reinterpret_cast<const ushort2*>(idc + (size_t)z * NN + i0);
    float2 c2 = *reinterpret_cast<const float2*>(cmean + (size_t)z * NN + i0);
    float v0 = (c2.x - mn) / (mx - mn);  // same normalize expression as before
    float v1 = (c2.y - mn) / (mx - mn);
    bool b0 = (id2.x == bst), b1 = (id2.y == bst);
    *reinterpret_cast<float2*>(out + 32 + (size_t)z * NN + i0) =
        make_float2(b0 ? v0 : 0.f, b1 ? v1 : 0.f);

    int h = (i0 >> 8) & (HH - 1);        // i0 even => both voxels share h
    int w = i0 & (WW - 1);
    int c1 = (int)b0 + (int)b1;
    int ch = (b0 ? h : 0) + (b1 ? h : 0);
    int cw = (b0 ? w : 0) + (b1 ? (w + 1) : 0);
    for (int o = 32; o; o >>= 1) {
        c1 += __shfl_down(c1, o); ch += __shfl_down(ch, o); cw += __shfl_down(cw, o);
    }
    __shared__ int s0[4], s1[4], s2[4];
    int wid = threadIdx.x >> 6, lane = threadIdx.x & 63;
    if (lane == 0) { s0[wid] = c1; s1[wid] = ch; s2[wid] = cw; }
    __syncthreads();
    if (threadIdx.x == 0) {
        c1 = s0[0] + s0[1] + s0[2] + s0[3];
        ch = s1[0] + s1[1] + s1[2] + s1[3];
        cw = s2[0] + s2[1] + s2[2] + s2[3];
        int* ct = cent + (z * BB + b) * 3;
        atomicAdd(&ct[0], c1); atomicAdd(&ct[1], ch); atomicAdd(&ct[2], cw);
    }
}

__global__ void k_final(const int* __restrict__ cent, float* __restrict__ out) {
    int b = threadIdx.x;
    if (b >= BB) return;
    const float PI = (float)M_PI;  // f32(np.pi)
    float th[3], ph[3];
    for (int z = 0; z < 3; z++) {
        const int* ct = cent + (z * BB + b) * 3;
        float cnt = (float)ct[0];
        float hm = (float)ct[1] / cnt;   // integer sums exact in f32 (< 2^24)
        float wm = (float)ct[2] / cnt;
        ph[z] = (0.5f - hm / (float)HH) * PI;
        th[z] = (wm / (float)WW - 0.5f) * 2.0f * PI;
    }
    auto dist = [PI](float t1, float p1, float t2, float p2) {
        float cosd = sinf(t1) * sinf(t2) + cosf(t1) * cosf(t2) * cosf(p1 - p2);
        float d = acosf(cosd);
        if (isnan(d)) d = 0.f;           // jnp.nan_to_num semantics
        return d / PI;
    };
    out[b]      = dist(th[0], ph[0], th[1], ph[1]);
    out[BB + b] = dist(th[1], ph[1], th[2], ph[2]);
}

extern "C" void kernel_launch(void* const* d_in, const int* in_sizes, int n_in,
                              void* d_out, int out_size, void* d_ws, size_t ws_size,
                              hipStream_t stream) {
    const float* x0 = (const float*)d_in[0];
    const float* x1 = (const float*)d_in[1];
    const float* x2 = (const float*)d_in[2];
    float* out = (float*)d_out;
    char* ws = (char*)d_ws;
    float*    cmean    = (float*)(ws + OFF_CMEAN);
    unsigned* parent   = (unsigned*)(ws + OFF_PARENT);
    unsigned* dense    = (unsigned*)(ws + OFF_DENSE);
    unsigned* rootlist = (unsigned*)(ws + OFF_ROOTLIST);
    int*      counts   = (int*)(ws + OFF_COUNTS);
    unsigned* rootlab  = (unsigned*)(ws + OFF_ROOTLAB);
    unsigned* mmkey    = (unsigned*)(ws + OFF_MMKEY);
    unsigned* Kc       = (unsigned*)(ws + OFF_K);
    unsigned* rootcnt  = (unsigned*)(ws + OFF_RCNT);
    unsigned* best     = (unsigned*)(ws + OFF_BEST);
    int*      cent     = (int*)(ws + OFF_CENT);
    unsigned short* idc = (unsigned short*)(ws + OFF_IDC);

    hipMemsetAsync(ws + OFF_COUNTS, 0, OFF_END - OFF_COUNTS, stream);
    hipLaunchKernelGGL(k_cmean_z<0>, dim3(HWs / 1024, BB), dim3(256), 0, stream, x0, cmean, mmkey);
    hipLaunchKernelGGL(k_cmean_z<1>, dim3(HWs / 1024, BB), dim3(256), 0, stream, x1, cmean, mmkey);
    hipLaunchKernelGGL(k_cmean_z<2>, dim3(HWs / 1024, BB), dim3(256), 0, stream, x2, cmean, mmkey);
    hipLaunchKernelGGL(k_mask_ccl, dim3(WW / TILE_W, HH / TILE_H, 3), dim3(TPB), 0, stream,
                       cmean, mmkey, parent, rootlist, rootcnt);
    hipLaunchKernelGGL(k_merge_tp, dim3((NPAIR + 3) / 4, 3), dim3(256), 0, stream, parent);
    hipLaunchKernelGGL(k_rootcompress, dim3(32, 3), dim3(256), 0, stream,
                       parent, rootlist, rootcnt, dense, rootlab, Kc);
    hipLaunchKernelGGL(k_count, dim3(NN / 512, 3), dim3(256), 0, stream, parent, dense, counts, idc);
    hipLaunchKernelGGL(k_best, dim3(BB, 3), dim3(256), 0, stream, counts, rootlab, Kc, best);
    hipLaunchKernelGGL(k_result, dim3(NN / 512, 3), dim3(256), 0, stream,
                       cmean, idc, mmkey, best, out, cent);
    hipLaunchKernelGGL(k_final, dim3(1), dim3(64), 0, stream, cent, out);
}

// Round 7
// 460.119 us; speedup vs baseline: 1.2809x; 1.0706x over previous
//
#include <hip/hip_runtime.h>
#include <math.h>

#define BB 16
#define CC 64
#define HH 128
#define WW 256
#define HWs 32768      // HH*WW
#define NN 524288      // BB*HH*WW
#define KMAX 8192
#define RCAP 65536     // tile-root list capacity per z
#define INV 0xFFFFFFFFu
#define INV16 0xFFFFu

// tile: full batch depth x 8h x 32w = 4096 voxels
#define TILE_H 8
#define TILE_W 32
#define TVOX 4096
#define TPB 1024       // mask_ccl block: halves serial LDS phase count vs 512
#define NROWS 128      // BB * TILE_H rows of 32 w-bits

// tile-pair boundaries (for the wave-per-pair merge)
#define NPW 112        // 7 internal w-boundaries * 16 h-tiles
#define NPH 120        // 15 internal h-boundaries * 8 w-tiles
#define NPAIR 232

// ---- workspace layout (bytes) ----
#define OFF_CMEAN    0                                   // f32 [3][NN]
#define OFF_PARENT   (OFF_CMEAN   + 3*NN*4)              // u32 [3][NN]
#define OFF_DENSE    (OFF_PARENT  + 3*NN*4)              // u32 [3][NN] (sparse: only roots)
#define OFF_ROOTLIST (OFF_DENSE   + 3*NN*4)              // u32 [3][RCAP] (not zeroed)
#define OFF_COUNTS   (OFF_ROOTLIST+ 3*RCAP*4)            // i32 [3][BB][KMAX]   <- zeroed from here
#define OFF_ROOTLAB  (OFF_COUNTS  + 3*BB*KMAX*4)         // u32 [3][KMAX]
#define OFF_MMKEY    (OFF_ROOTLAB + 3*KMAX*4)            // u32 [3][BB][2] (~minkey,maxkey), both atomicMax
#define OFF_K        (OFF_MMKEY   + 3*BB*2*4)            // u32 [3] (+pad)
#define OFF_RCNT     (OFF_K       + 16)                  // u32 [3] (+pad)
#define OFF_BEST     (OFF_RCNT    + 16)                  // u32 [3][BB]
#define OFF_CENT     (OFF_BEST    + 3*BB*4)              // i32 [3][BB][3]
#define OFF_END      (OFF_CENT    + 3*BB*3*4)
#define OFF_IDC      OFF_END                             // u16 [3][NN] per-voxel dense id (fully overwritten)

// monotone float<->uint key (order-preserving incl. negatives)
__device__ __forceinline__ unsigned f2key(float f) {
    unsigned u = __float_as_uint(f);
    return (u & 0x80000000u) ? ~u : (u | 0x80000000u);
}
__device__ __forceinline__ float key2f(unsigned k) {
    unsigned u = (k & 0x80000000u) ? (k ^ 0x80000000u) : ~k;
    return __uint_as_float(u);
}

// ---- union-find, links always point to LARGER index => root = max linear idx ----
__device__ unsigned uf_find(unsigned* p, unsigned i) {
    while (true) {
        unsigned pi = ((volatile unsigned*)p)[i];
        if (pi == i) return i;
        unsigned gp = ((volatile unsigned*)p)[pi];
        if (gp != pi) ((volatile unsigned*)p)[i] = gp;  // path halving (monotone, safe)
        i = pi;
    }
}
__device__ void uf_union(unsigned* p, unsigned a, unsigned b) {
    while (true) {
        a = uf_find(p, a);
        b = uf_find(p, b);
        if (a == b) return;
        if (a < b) { unsigned t = a; a = b; b = t; }   // a = max root
        unsigned old = atomicCAS(&p[b], b, a);
        if (old == b) return;
        b = old;
    }
}

// ---- LDS union-find (same invariants, shared-memory atomics) ----
__device__ __forceinline__ unsigned lfind(unsigned* p, unsigned i) {
    while (true) {
        unsigned pi = ((volatile unsigned*)p)[i];
        if (pi == i) return i;
        unsigned gp = ((volatile unsigned*)p)[pi];
        if (gp != pi) ((volatile unsigned*)p)[i] = gp;
        i = pi;
    }
}
__device__ void lunion(unsigned* p, unsigned a, unsigned b) {
    while (true) {
        a = lfind(p, a);
        b = lfind(p, b);
        if (a == b) return;
        if (a < b) { unsigned t = a; a = b; b = t; }
        unsigned old = atomicCAS(&p[b], b, a);
        if (old == b) return;
        b = old;
    }
}

// wave-level dedup'd union: one uf_union per DISTINCT (root,root) pair per call.
// All 64 lanes of the wave must enter together.
__device__ __forceinline__ void wave_union(unsigned* p, unsigned pi, unsigned pj, int lane) {
    bool valid = (pi != INV) && (pj != INV) && (pi != pj);
    unsigned lo = pi < pj ? pi : pj;
    unsigned hi = pi < pj ? pj : pi;
    unsigned long long key = valid ? (((unsigned long long)hi << 32) | lo) : ~0ull;
    unsigned long long rem = __ballot(valid);
    while (rem) {
        int leader = __ffsll((long long)rem) - 1;
        unsigned long long lkey = __shfl(key, leader);
        unsigned long long m = __ballot(valid && key == lkey) & rem;
        if (lane == leader) uf_union(p, pi, pj);
        rem &= ~m;
    }
}

// channel mean + per-sample min/max, ONE z per dispatch. At the ~3.1 TB/s
// read-path roofline (402 MB mandatory reads): verified optimal rounds 0-6.
// Per-element summation tree identical across rounds => bit-identical cmean.
template<int Z>
__global__ void k_cmean_z(const float* __restrict__ x, float* __restrict__ cmean,
                          unsigned* __restrict__ mmkey) {
    int b = blockIdx.y, t = threadIdx.x;
    int hw = blockIdx.x * 1024 + t * 4;
    const float* px = x + (size_t)b * CC * HWs + hw;
    float4 a0 = make_float4(0.f, 0.f, 0.f, 0.f), a1 = a0, a2 = a0, a3 = a0;
#pragma unroll
    for (int c = 0; c < CC; c += 4) {
        float4 v0 = *reinterpret_cast<const float4*>(px + (size_t)(c + 0) * HWs);
        float4 v1 = *reinterpret_cast<const float4*>(px + (size_t)(c + 1) * HWs);
        float4 v2 = *reinterpret_cast<const float4*>(px + (size_t)(c + 2) * HWs);
        float4 v3 = *reinterpret_cast<const float4*>(px + (size_t)(c + 3) * HWs);
        a0.x += v0.x; a0.y += v0.y; a0.z += v0.z; a0.w += v0.w;
        a1.x += v1.x; a1.y += v1.y; a1.z += v1.z; a1.w += v1.w;
        a2.x += v2.x; a2.y += v2.y; a2.z += v2.z; a2.w += v2.w;
        a3.x += v3.x; a3.y += v3.y; a3.z += v3.z; a3.w += v3.w;
    }
    const float inv = 1.f / 64.f;   // /64 exact pow2
    float4 s;
    s.x = ((a0.x + a1.x) + (a2.x + a3.x)) * inv;
    s.y = ((a0.y + a1.y) + (a2.y + a3.y)) * inv;
    s.z = ((a0.z + a1.z) + (a2.z + a3.z)) * inv;
    s.w = ((a0.w + a1.w) + (a2.w + a3.w)) * inv;
    float* cm = cmean + (size_t)Z * NN + (size_t)b * HWs + hw;
    *reinterpret_cast<float4*>(cm) = s;

    float mn = fminf(fminf(s.x, s.y), fminf(s.z, s.w));
    float mx = fmaxf(fmaxf(s.x, s.y), fmaxf(s.z, s.w));
    for (int o = 32; o; o >>= 1) {
        mn = fminf(mn, __shfl_down(mn, o));
        mx = fmaxf(mx, __shfl_down(mx, o));
    }
    __shared__ float smn[4], smx[4];
    int wid = t >> 6, lane = t & 63;
    if (lane == 0) { smn[wid] = mn; smx[wid] = mx; }
    __syncthreads();
    if (t == 0) {
        mn = fminf(fminf(smn[0], smn[1]), fminf(smn[2], smn[3]));
        mx = fmaxf(fmaxf(smx[0], smx[1]), fmaxf(smx[2], smx[3]));
        atomicMax(&mmkey[(Z * BB + b) * 2 + 0], ~f2key(mn));
        atomicMax(&mmkey[(Z * BB + b) * 2 + 1], f2key(mx));
    }
}

// fused: normalize -> mask -> LOCAL run-based CCL over a [16b x 8h x 32w] tile.
// NOW 1024 threads (4 serial phases instead of 8): the kernel is a ladder of
// serial LDS passes, so phase count is the latency lever. Logic unchanged.
__global__ void __launch_bounds__(TPB) k_mask_ccl(const float* __restrict__ cmean,
                                                  const unsigned* __restrict__ mmkey,
                                                  unsigned* __restrict__ parent_all,
                                                  unsigned* __restrict__ rootlist,
                                                  unsigned* __restrict__ rootcnt) {
    int z = blockIdx.z;
    int h0 = blockIdx.y * TILE_H;
    int w0 = blockIdx.x * TILE_W;
    int t = threadIdx.x;
    int lane = t & 63;
    __shared__ unsigned sp[TVOX];
    __shared__ unsigned rowmask[NROWS];
    __shared__ float smn[BB], smx[BB];
    __shared__ unsigned lcnt, sbase;
    if (t == 0) lcnt = 0;
    if (t < BB) {
        smn[t] = key2f(~mmkey[(z * BB + t) * 2 + 0]);
        smx[t] = key2f(mmkey[(z * BB + t) * 2 + 1]);
    }
    __syncthreads();
#pragma unroll
    for (int ph = 0; ph < TVOX / TPB; ph++) {
        int li = ph * TPB + t;
        int lb = li >> 8, lh = (li >> 5) & 7, lw = li & 31;
        unsigned gi = lb * HWs + (h0 + lh) * WW + (w0 + lw);
        float c = cmean[(size_t)z * NN + gi];
        bool mkd = (c - smn[lb]) / (smx[lb] - smn[lb]) >= 0.4f;
        unsigned long long bal = __ballot(mkd);
        unsigned m = (lane < 32) ? (unsigned)bal : (unsigned)(bal >> 32);
        int row = li >> 5;
        if ((lane & 31) == 0) rowmask[row] = m;
        unsigned v = INV;
        if (mkd) {
            int j = __ffsll(~((unsigned long long)m >> lw)) - 1;  // trailing-ones >=1
            v = (unsigned)((row << 5) + lw + j - 1);              // run root (run max)
        }
        sp[li] = v;
    }
    __syncthreads();
#pragma unroll
    for (int ph = 0; ph < TVOX / TPB; ph++) {
        int li = ph * TPB + t;
        int row = li >> 5, lw = li & 31;
        unsigned m = rowmask[row];
        if (!((m >> lw) & 1)) continue;
        int lh = row & 7;
        if (lh < TILE_H - 1) {                       // h-edge, row -> row+1
            unsigned m2 = rowmask[row + 1];
            unsigned ov = m & m2;
            bool leader = ((ov >> lw) & 1) && (lw == 0 || !((ov >> (lw - 1)) & 1));
            if (leader) {
                int j2 = __ffsll(~((unsigned long long)m2 >> lw)) - 1;
                lunion(sp, sp[li], (unsigned)(((row + 1) << 5) + lw + j2 - 1));
            }
        }
        if (row < NROWS - 8) {                       // b-edge, row -> row+8
            unsigned m2 = rowmask[row + 8];
            unsigned ov = m & m2;
            bool leader = ((ov >> lw) & 1) && (lw == 0 || !((ov >> (lw - 1)) & 1));
            if (leader) {
                int j2 = __ffsll(~((unsigned long long)m2 >> lw)) - 1;
                lunion(sp, sp[li], (unsigned)(((row + 8) << 5) + lw + j2 - 1));
            }
        }
    }
    __syncthreads();
    // pointer-jump flatten: tree static now; races only move entries rootward
#pragma unroll
    for (int it = 0; it < 4; it++) {
#pragma unroll
        for (int ph = 0; ph < TVOX / TPB; ph++) {
            int li = ph * TPB + t;
            unsigned v = sp[li];
            if (v != INV) {
                unsigned w = sp[v];
                if (w != v) sp[li] = w;
            }
        }
    }
    __syncthreads();
    unsigned myroot[TVOX / TPB];
    unsigned myoff[TVOX / TPB];
    int nmy = 0;
#pragma unroll
    for (int ph = 0; ph < TVOX / TPB; ph++) {
        int li = ph * TPB + t;
        int lb = li >> 8, lh = (li >> 5) & 7, lw = li & 31;
        unsigned gi = lb * HWs + (h0 + lh) * WW + (w0 + lw);
        unsigned v = sp[li];
        if (v != INV) {
            unsigned r = v;
            while (sp[r] != r) r = sp[r];           // short after flatten
            int rb = r >> 8, rh = (r >> 5) & 7, rw = r & 31;
            v = rb * HWs + (h0 + rh) * WW + (w0 + rw);
            if (r == (unsigned)li) {                // tile root -> record
                myroot[nmy] = gi;
                myoff[nmy] = atomicAdd(&lcnt, 1u);
                nmy++;
            }
        }
        parent_all[(size_t)z * NN + gi] = v;
    }
    __syncthreads();
    if (t == 0) sbase = atomicAdd(&rootcnt[z], lcnt);
    __syncthreads();
    for (int k = 0; k < nmy; k++) {
        unsigned idx = sbase + myoff[k];
        if (idx < RCAP) rootlist[(size_t)z * RCAP + idx] = myroot[k];
    }
}

// cross-tile merge, ONE WAVE PER TILE-PAIR BOUNDARY (verified round 4: removed
// the 80us CAS/coherence stall of the per-edge version).
__global__ void k_merge_tp(unsigned* __restrict__ parent_all) {
    int z = blockIdx.y;
    unsigned* p = parent_all + (size_t)z * NN;
    int pair = blockIdx.x * 4 + (threadIdx.x >> 6);   // wave-uniform
    if (pair >= NPAIR) return;
    int lane = threadIdx.x & 63;
    if (pair < NPW) {
        // w-boundary: column w = wb*32+31, tile-row ht; cells = 16b x 8h = 128
        int wb = pair / 16, ht = pair % 16;
        int w = wb * TILE_W + (TILE_W - 1);
#pragma unroll
        for (int r = 0; r < 2; r++) {
            int c = r * 64 + lane;
            int b = c >> 3, lh = c & 7;
            unsigned i = b * HWs + (ht * TILE_H + lh) * WW + w;
            wave_union(p, p[i], p[i + 1], lane);
        }
    } else {
        // h-boundary: row h = hb*8+7, tile-col wt; cells = 16b x 32w = 512
        int e = pair - NPW;
        int hb = e / 8, wt = e % 8;
        int h = hb * TILE_H + (TILE_H - 1);
#pragma unroll
        for (int r = 0; r < 8; r++) {
            int c = r * 64 + lane;
            int b = c >> 5, lw = c & 31;
            unsigned i = b * HWs + h * WW + wt * TILE_W + lw;
            wave_union(p, p[i], p[i + WW], lane);
        }
    }
}

// compress ONLY tile roots (p[t] -> global root) + dense-id the global roots.
// After this, root(voxel i) == p[p[i]] exactly, with no NN-wide write pass.
__global__ void k_rootcompress(unsigned* __restrict__ parent_all,
                               const unsigned* __restrict__ rootlist,
                               const unsigned* __restrict__ rootcnt,
                               unsigned* __restrict__ dense_all,
                               unsigned* __restrict__ rootlab, unsigned* __restrict__ Kc) {
    int z = blockIdx.y;
    unsigned* p = parent_all + (size_t)z * NN;
    unsigned cnt = rootcnt[z]; if (cnt > RCAP) cnt = RCAP;
    for (unsigned j = blockIdx.x * 256 + threadIdx.x; j < cnt; j += gridDim.x * 256) {
        unsigned r = rootlist[(size_t)z * RCAP + j];
        unsigned g = uf_find(p, r);
        p[r] = g;
        if (g == r) {
            unsigned id = atomicAdd(&Kc[z], 1u);
            if (id >= KMAX) id = KMAX - 1;   // never expected
            dense_all[(size_t)z * NN + g] = id;
            rootlab[z * KMAX + id] = g;
        }
    }
}

// per-slice per-component counts + CACHE the resolved per-voxel dense id into
// idc (u16). 4 voxels/thread, uint4 parent load: 4 independent gather chains
// per thread for latency hiding. root = p[p[i]].
__global__ void k_count(const unsigned* __restrict__ parent_all,
                        const unsigned* __restrict__ dense_all, int* __restrict__ counts,
                        unsigned short* __restrict__ idc) {
    int z = blockIdx.y;
    const unsigned* p = parent_all + (size_t)z * NN;
    const unsigned* d = dense_all + (size_t)z * NN;
    unsigned i0 = (blockIdx.x * 256u + threadIdx.x) * 4u;
    int b = i0 >> 15;   // uniform across the wave (256 consecutive voxels/wave)
    uint4 pp = *reinterpret_cast<const uint4*>(p + i0);
    unsigned id[4] = { INV16, INV16, INV16, INV16 };
    unsigned r0 = (pp.x != INV) ? p[pp.x] : INV;
    unsigned r1 = (pp.y != INV) ? p[pp.y] : INV;
    unsigned r2 = (pp.z != INV) ? p[pp.z] : INV;
    unsigned r3 = (pp.w != INV) ? p[pp.w] : INV;
    if (r0 != INV) id[0] = d[r0];
    if (r1 != INV) id[1] = d[r1];
    if (r2 != INV) id[2] = d[r2];
    if (r3 != INV) id[3] = d[r3];
    *reinterpret_cast<ushort4*>(idc + (size_t)z * NN + i0) =
        make_ushort4((unsigned short)id[0], (unsigned short)id[1],
                     (unsigned short)id[2], (unsigned short)id[3]);
    int lane = threadIdx.x & 63;
    int* crow = counts + ((size_t)z * BB + b) * KMAX;
#pragma unroll
    for (int q = 0; q < 4; q++) {
        unsigned idq = id[q];
        bool valid = idq != INV16;
        unsigned long long rem = __ballot(valid);
        while (rem) {
            int leader = __ffsll((long long)rem) - 1;
            unsigned lid = __shfl(idq, leader);
            unsigned long long m = __ballot(valid && idq == lid) & rem;
            if (lane == leader) atomicAdd(&crow[lid], (int)__popcll(m));
            rem &= ~m;
        }
    }
}

// per-slice argmax: max count, tie -> smallest root label (== reference argmax semantics)
__global__ void k_best(const int* __restrict__ counts, const unsigned* __restrict__ rootlab,
                       const unsigned* __restrict__ Kc, unsigned* __restrict__ best) {
    int z = blockIdx.y, b = blockIdx.x, t = threadIdx.x;
    const int* crow = counts + ((size_t)z * BB + b) * KMAX;
    const unsigned* rl = rootlab + z * KMAX;
    unsigned K = Kc[z]; if (K > KMAX) K = KMAX;
    int bc = -1; unsigned brl = INV; int bj = 0;
    for (unsigned j = t; j < K; j += blockDim.x) {
        int c = crow[j]; unsigned r = rl[j];
        if (c > bc || (c == bc && r < brl)) { bc = c; brl = r; bj = (int)j; }
    }
    __shared__ int sc[256]; __shared__ unsigned sr[256]; __shared__ int sj[256];
    sc[t] = bc; sr[t] = brl; sj[t] = bj;
    __syncthreads();
    for (int o = 128; o; o >>= 1) {
        if (t < o) {
            int c2 = sc[t + o]; unsigned r2 = sr[t + o];
            if (c2 > sc[t] || (c2 == sc[t] && r2 < sr[t])) { sc[t] = c2; sr[t] = r2; sj[t] = sj[t + o]; }
        }
        __syncthreads();
    }
    if (t == 0) best[z * BB + b] = (unsigned)sj[0];
}

// masked normalized output + integer centroid sums — pure streaming, 4/thread.
__global__ void k_result(const float* __restrict__ cmean, const unsigned short* __restrict__ idc,
                         const unsigned* __restrict__ mmkey, const unsigned* __restrict__ best,
                         float* __restrict__ out, int* __restrict__ cent) {
    int z = blockIdx.y;
    unsigned i0 = (blockIdx.x * 256u + threadIdx.x) * 4u;
    int b = i0 >> 15;   // uniform per block (1024 consecutive voxels)
    float mn = key2f(~mmkey[(z * BB + b) * 2 + 0]);
    float mx = key2f(mmkey[(z * BB + b) * 2 + 1]);
    unsigned short bst = (unsigned short)best[z * BB + b];
    ushort4 id4 = *reinterpret_cast<const ushort4*>(idc + (size_t)z * NN + i0);
    float4 c4 = *reinterpret_cast<const float4*>(cmean + (size_t)z * NN + i0);
    float rs = 1.f;   // keep exact (c-mn)/(mx-mn) expression
    (void)rs;
    float v0 = (c4.x - mn) / (mx - mn);
    float v1 = (c4.y - mn) / (mx - mn);
    float v2 = (c4.z - mn) / (mx - mn);
    float v3 = (c4.w - mn) / (mx - mn);
    bool b0 = (id4.x == bst), b1 = (id4.y == bst), b2 = (id4.z == bst), b3 = (id4.w == bst);
    *reinterpret_cast<float4*>(out + 32 + (size_t)z * NN + i0) =
        make_float4(b0 ? v0 : 0.f, b1 ? v1 : 0.f, b2 ? v2 : 0.f, b3 ? v3 : 0.f);

    int h = (i0 >> 8) & (HH - 1);        // i0 mult of 4 => all 4 voxels share h
    int w = i0 & (WW - 1);
    int c1 = (int)b0 + (int)b1 + (int)b2 + (int)b3;
    int ch = ((int)b0 + (int)b1 + (int)b2 + (int)b3) * h;
    int cw = (b0 ? w : 0) + (b1 ? (w + 1) : 0) + (b2 ? (w + 2) : 0) + (b3 ? (w + 3) : 0);
    for (int o = 32; o; o >>= 1) {
        c1 += __shfl_down(c1, o); ch += __shfl_down(ch, o); cw += __shfl_down(cw, o);
    }
    __shared__ int s0[4], s1[4], s2[4];
    int wid = threadIdx.x >> 6, lane = threadIdx.x & 63;
    if (lane == 0) { s0[wid] = c1; s1[wid] = ch; s2[wid] = cw; }
    __syncthreads();
    if (threadIdx.x == 0) {
        c1 = s0[0] + s0[1] + s0[2] + s0[3];
        ch = s1[0] + s1[1] + s1[2] + s1[3];
        cw = s2[0] + s2[1] + s2[2] + s2[3];
        int* ct = cent + (z * BB + b) * 3;
        atomicAdd(&ct[0], c1); atomicAdd(&ct[1], ch); atomicAdd(&ct[2], cw);
    }
}

__global__ void k_final(const int* __restrict__ cent, float* __restrict__ out) {
    int b = threadIdx.x;
    if (b >= BB) return;
    const float PI = (float)M_PI;  // f32(np.pi)
    float th[3], ph[3];
    for (int z = 0; z < 3; z++) {
        const int* ct = cent + (z * BB + b) * 3;
        float cnt = (float)ct[0];
        float hm = (float)ct[1] / cnt;   // integer sums exact in f32 (< 2^24)
        float wm = (float)ct[2] / cnt;
        ph[z] = (0.5f - hm / (float)HH) * PI;
        th[z] = (wm / (float)WW - 0.5f) * 2.0f * PI;
    }
    auto dist = [PI](float t1, float p1, float t2, float p2) {
        float cosd = sinf(t1) * sinf(t2) + cosf(t1) * cosf(t2) * cosf(p1 - p2);
        float d = acosf(cosd);
        if (isnan(d)) d = 0.f;           // jnp.nan_to_num semantics
        return d / PI;
    };
    out[b]      = dist(th[0], ph[0], th[1], ph[1]);
    out[BB + b] = dist(th[1], ph[1], th[2], ph[2]);
}

extern "C" void kernel_launch(void* const* d_in, const int* in_sizes, int n_in,
                              void* d_out, int out_size, void* d_ws, size_t ws_size,
                              hipStream_t stream) {
    const float* x0 = (const float*)d_in[0];
    const float* x1 = (const float*)d_in[1];
    const float* x2 = (const float*)d_in[2];
    float* out = (float*)d_out;
    char* ws = (char*)d_ws;
    float*    cmean    = (float*)(ws + OFF_CMEAN);
    unsigned* parent   = (unsigned*)(ws + OFF_PARENT);
    unsigned* dense    = (unsigned*)(ws + OFF_DENSE);
    unsigned* rootlist = (unsigned*)(ws + OFF_ROOTLIST);
    int*      counts   = (int*)(ws + OFF_COUNTS);
    unsigned* rootlab  = (unsigned*)(ws + OFF_ROOTLAB);
    unsigned* mmkey    = (unsigned*)(ws + OFF_MMKEY);
    unsigned* Kc       = (unsigned*)(ws + OFF_K);
    unsigned* rootcnt  = (unsigned*)(ws + OFF_RCNT);
    unsigned* best     = (unsigned*)(ws + OFF_BEST);
    int*      cent     = (int*)(ws + OFF_CENT);
    unsigned short* idc = (unsigned short*)(ws + OFF_IDC);

    hipMemsetAsync(ws + OFF_COUNTS, 0, OFF_END - OFF_COUNTS, stream);
    hipLaunchKernelGGL(k_cmean_z<0>, dim3(HWs / 1024, BB), dim3(256), 0, stream, x0, cmean, mmkey);
    hipLaunchKernelGGL(k_cmean_z<1>, dim3(HWs / 1024, BB), dim3(256), 0, stream, x1, cmean, mmkey);
    hipLaunchKernelGGL(k_cmean_z<2>, dim3(HWs / 1024, BB), dim3(256), 0, stream, x2, cmean, mmkey);
    hipLaunchKernelGGL(k_mask_ccl, dim3(WW / TILE_W, HH / TILE_H, 3), dim3(TPB), 0, stream,
                       cmean, mmkey, parent, rootlist, rootcnt);
    hipLaunchKernelGGL(k_merge_tp, dim3((NPAIR + 3) / 4, 3), dim3(256), 0, stream, parent);
    hipLaunchKernelGGL(k_rootcompress, dim3(32, 3), dim3(256), 0, stream,
                       parent, rootlist, rootcnt, dense, rootlab, Kc);
    hipLaunchKernelGGL(k_count, dim3(NN / 1024, 3), dim3(256), 0, stream, parent, dense, counts, idc);
    hipLaunchKernelGGL(k_best, dim3(BB, 3), dim3(256), 0, stream, counts, rootlab, Kc, best);
    hipLaunchKernelGGL(k_result, dim3(NN / 1024, 3), dim3(256), 0, stream,
                       cmean, idc, mmkey, best, out, cent);
    hipLaunchKernelGGL(k_final, dim3(1), dim3(64), 0, stream, cent, out);
}